// Round 1
// baseline (544.430 us; speedup 1.0000x reference)
//
#include <hip/hip_runtime.h>

#define B   8
#define S   16
#define C   32
#define P   64
#define E   768
#define M   512       // S*C
#define LL  32768     // M*P
#define NE  1000000

// ---------------------------------------------------------------------------
// K1: sum1[b, m] = sum_p att[b, m*64+p] * dot(emb[ids[b,m*64+p]], span[b, m%16])
// One 256-thread block (4 waves) per segment. Each wave covers a full 768-float
// row (3 float4 per lane), handles 16 of the 64 bag members.
// ---------------------------------------------------------------------------
__global__ __launch_bounds__(256) void k1_gather_dot(
    const float* __restrict__ emb,     // (T, 768)
    const int*   __restrict__ ids,     // (B, LL)
    const float* __restrict__ att,     // (B, LL)
    const float* __restrict__ span,    // (B, 16, 768)
    float*       __restrict__ sum1)    // (B*512)
{
    const int seg  = blockIdx.x;          // b*512 + m
    const int b    = seg >> 9;
    const int m    = seg & 511;
    const int lane = threadIdx.x & 63;
    const int wave = threadIdx.x >> 6;

    const float4* sp = reinterpret_cast<const float4*>(span + (size_t)(b * S + (m & 15)) * E);
    const float4 s0 = sp[lane];
    const float4 s1 = sp[lane + 64];
    const float4 s2 = sp[lane + 128];

    const size_t base = (size_t)b * LL + (size_t)m * P;
    float acc = 0.f;
    #pragma unroll 4
    for (int p = wave; p < P; p += 4) {
        const int   id = ids[base + p];
        const float a  = att[base + p];
        const float4* row = reinterpret_cast<const float4*>(emb + (size_t)id * E);
        const float4 r0 = row[lane];
        const float4 r1 = row[lane + 64];
        const float4 r2 = row[lane + 128];
        float d = r0.x*s0.x + r0.y*s0.y + r0.z*s0.z + r0.w*s0.w
                + r1.x*s1.x + r1.y*s1.y + r1.z*s1.z + r1.w*s1.w
                + r2.x*s2.x + r2.y*s2.y + r2.z*s2.z + r2.w*s2.w;
        acc = fmaf(a, d, acc);
    }
    #pragma unroll
    for (int off = 32; off > 0; off >>= 1)
        acc += __shfl_down(acc, off, 64);

    __shared__ float red[4];
    if (lane == 0) red[wave] = acc;
    __syncthreads();
    if (threadIdx.x == 0)
        sum1[seg] = red[0] + red[1] + red[2] + red[3];
}

// ---------------------------------------------------------------------------
// K2: per-batch. span_scores, softmax over S per (c), softmax over M,
// scatter cand_scores into out (out pre-zeroed).
// thread t = s*32 + c.
// ---------------------------------------------------------------------------
__global__ __launch_bounds__(512) void k2_softmax_scatter(
    const float* __restrict__ sum1,    // (B, 512)
    const float* __restrict__ span,    // (B, 16, 768)
    const float* __restrict__ spanW,   // (768)
    const float* __restrict__ spanb,   // (1)
    const int*   __restrict__ qids,    // (B, 512)
    float*       __restrict__ out)     // (B, NE)
{
    const int b = blockIdx.x;
    const int t = threadIdx.x;

    __shared__ float ls[512];
    __shared__ float ss[16];

    // span_scores: 16 groups of 32 threads, each group dots one span row
    {
        const int s = t >> 5, j = t & 31;
        const float* sp = span + (size_t)(b * S + s) * E;
        float partial = 0.f;
        for (int e = j; e < E; e += 32) partial = fmaf(sp[e], spanW[e], partial);
        #pragma unroll
        for (int off = 16; off > 0; off >>= 1) partial += __shfl_down(partial, off, 32);
        if (j == 0) ss[s] = partial + spanb[0];
    }

    const float v = sum1[b * M + t];
    ls[t] = v;
    __syncthreads();

    // softmax over s (16 values at stride 32) for this thread's column c
    const int c = t & 31;
    float mx = -1e30f;
    #pragma unroll
    for (int s2 = 0; s2 < S; ++s2) mx = fmaxf(mx, ls[s2 * 32 + c]);
    float den = 0.f;
    #pragma unroll
    for (int s2 = 0; s2 < S; ++s2) den += expf(ls[s2 * 32 + c] - mx);
    const float sm1v = expf(v - mx) / den;
    const float m2   = ss[t >> 5] * sm1v;
    __syncthreads();

    // softmax over all 512
    ls[t] = m2; __syncthreads();
    for (int off = 256; off > 0; off >>= 1) {
        if (t < off) ls[t] = fmaxf(ls[t], ls[t + off]);
        __syncthreads();
    }
    const float bigM = ls[0];
    __syncthreads();
    const float ex = expf(m2 - bigM);
    ls[t] = ex; __syncthreads();
    for (int off = 256; off > 0; off >>= 1) {
        if (t < off) ls[t] += ls[t + off];
        __syncthreads();
    }
    const float cand = ex / ls[0];

    const int q = qids[b * M + t];
    if (q < NE) atomicAdd(&out[(size_t)b * NE + q], cand);
}

// ---------------------------------------------------------------------------
// K3: per-batch denominator of the 1M-wide softmax WITHOUT reading the array:
// denom = NE + sum over DISTINCT touched qids of (exp(v) - 1).
// O(512^2) LDS dedup. No max subtraction (values <= ~1, exp is exact enough).
// ---------------------------------------------------------------------------
__global__ __launch_bounds__(512) void k3_denom(
    const int*   __restrict__ qids,    // (B, 512)
    const float* __restrict__ out,     // (B, NE) post-scatter
    float*       __restrict__ invden)  // (B)
{
    const int b = blockIdx.x;
    const int t = threadIdx.x;
    __shared__ int   q[512];
    __shared__ float red[512];

    q[t] = qids[b * M + t];
    __syncthreads();

    float corr = 0.f;
    const int myq = q[t];
    if (myq < NE) {
        bool owner = true;
        for (int j = 0; j < t; ++j)
            if (q[j] == myq) { owner = false; break; }
        if (owner) corr = expf(out[(size_t)b * NE + myq]) - 1.f;
    }
    red[t] = corr;
    __syncthreads();
    for (int off = 256; off > 0; off >>= 1) {
        if (t < off) red[t] += red[t + off];
        __syncthreads();
    }
    if (t == 0) invden[b] = 1.f / (1.0e6f + red[0]);
}

// ---------------------------------------------------------------------------
// K4: out[b,i] = exp(out[b,i]) * invden[b], vectorized float4 in-place.
// ---------------------------------------------------------------------------
__global__ __launch_bounds__(256) void k4_finalize(
    float*       __restrict__ out,
    const float* __restrict__ invden)
{
    const int N4 = (B * NE) / 4;   // 2,000,000
    const int i  = blockIdx.x * blockDim.x + threadIdx.x;
    if (i >= N4) return;
    const int   b   = i / (NE / 4);
    const float inv = invden[b];
    float4* o4 = reinterpret_cast<float4*>(out);
    float4 v = o4[i];
    v.x = expf(v.x) * inv;
    v.y = expf(v.y) * inv;
    v.z = expf(v.z) * inv;
    v.w = expf(v.w) * inv;
    o4[i] = v;
}

extern "C" void kernel_launch(void* const* d_in, const int* in_sizes, int n_in,
                              void* d_out, int out_size, void* d_ws, size_t ws_size,
                              hipStream_t stream)
{
    (void)in_sizes; (void)n_in; (void)out_size; (void)ws_size;

    const float* span_embs = (const float*)d_in[0];  // (B,S,E)
    const int*   ids       = (const int*)  d_in[1];  // (B,LL)
    // d_in[2]: offsets_tr — fixed arange(M)*P structure, not needed
    const float* att       = (const float*)d_in[3];  // (B,LL)
    const int*   qids      = (const int*)  d_in[4];  // (B,M)
    const float* emb       = (const float*)d_in[5];  // (T,E)
    const float* spanW     = (const float*)d_in[6];  // (E)
    const float* spanb     = (const float*)d_in[7];  // (1)

    float* out    = (float*)d_out;
    float* sum1   = (float*)d_ws;       // B*M floats
    float* invden = sum1 + B * M;       // B floats

    hipMemsetAsync(d_out, 0, (size_t)B * NE * sizeof(float), stream);

    k1_gather_dot<<<B * M, 256, 0, stream>>>(emb, ids, att, span_embs, sum1);
    k2_softmax_scatter<<<B, 512, 0, stream>>>(sum1, span_embs, spanW, spanb, qids, out);
    k3_denom<<<B, 512, 0, stream>>>(qids, out, invden);
    k4_finalize<<<((B * NE / 4) + 255) / 256, 256, 0, stream>>>(out, invden);
}